// Round 5
// baseline (335.506 us; speedup 1.0000x reference)
//
#include <hip/hip_runtime.h>

#define KSTATES 64

__device__ __forceinline__ float wave_max64(float v) {
#pragma unroll
  for (int off = 32; off; off >>= 1) v = fmaxf(v, __shfl_xor(v, off, 64));
  return v;
}

__device__ __forceinline__ float wave_sum64(float v) {
#pragma unroll
  for (int off = 32; off; off >>= 1) v += __shfl_xor(v, off, 64);
  return v;
}

__device__ __forceinline__ float bcast0(float v) {
  return __int_as_float(__builtin_amdgcn_readfirstlane(__float_as_int(v)));
}

// 8 broadcasts: lanes (B..B+7) of av -> SGPR temps, as ONE volatile asm
// block so the compiler cannot re-sink individual readlanes next to their
// consumers (R3 showed it does exactly that at source level).
#define RL8(t, av, B)                                                         \
  asm volatile("v_readlane_b32 %0, %8, %9\n\t"                                \
               "v_readlane_b32 %1, %8, %10\n\t"                               \
               "v_readlane_b32 %2, %8, %11\n\t"                               \
               "v_readlane_b32 %3, %8, %12\n\t"                               \
               "v_readlane_b32 %4, %8, %13\n\t"                               \
               "v_readlane_b32 %5, %8, %14\n\t"                               \
               "v_readlane_b32 %6, %8, %15\n\t"                               \
               "v_readlane_b32 %7, %8, %16\n\t"                               \
               : "=&s"(t[0]), "=&s"(t[1]), "=&s"(t[2]), "=&s"(t[3]),          \
                 "=&s"(t[4]), "=&s"(t[5]), "=&s"(t[6]), "=&s"(t[7])           \
               : "v"(av), "n"(B + 0), "n"(B + 1), "n"(B + 2), "n"(B + 3),     \
                 "n"(B + 4), "n"(B + 5), "n"(B + 6), "n"(B + 7))

// First readlane group of a step: av was just written by a VALU v_mul, and
// VALU-writes-VGPR -> v_readlane-reads-it is a SOFTWARE-managed hazard the
// compiler's hazard recognizer cannot fix inside an asm body (this is what
// silently corrupted R4: stale av reads, absmax 640). s_nop 4 = 5 wait
// cycles covers every documented gfx9-class wait-state count. All later
// readlane->SGPR->v_fmac consumptions are covered by >=15 real instructions
// of pipelined distance, no nops needed there.
#define RL8_FIRST(t, av, B)                                                   \
  asm volatile("s_nop 4\n\t"                                                  \
               "v_readlane_b32 %0, %8, %9\n\t"                                \
               "v_readlane_b32 %1, %8, %10\n\t"                               \
               "v_readlane_b32 %2, %8, %11\n\t"                               \
               "v_readlane_b32 %3, %8, %12\n\t"                               \
               "v_readlane_b32 %4, %8, %13\n\t"                               \
               "v_readlane_b32 %5, %8, %14\n\t"                               \
               "v_readlane_b32 %6, %8, %15\n\t"                               \
               "v_readlane_b32 %7, %8, %16\n\t"                               \
               : "=&s"(t[0]), "=&s"(t[1]), "=&s"(t[2]), "=&s"(t[3]),          \
                 "=&s"(t[4]), "=&s"(t[5]), "=&s"(t[6]), "=&s"(t[7])           \
               : "v"(av), "n"(B + 0), "n"(B + 1), "n"(B + 2), "n"(B + 3),     \
                 "n"(B + 4), "n"(B + 5), "n"(B + 6), "n"(B + 7))

// 8 fmacs consuming one RL8 group. SGPR is src0 (vsrc1 must be VGPR).
// Chain rotation acc0..acc3 keeps dep distance 4 insts (8 cy >= 4 cy lat).
// Accumulation order identical to R2/R3: acc_k sums i == k (mod 4),
// increasing i -> bit-identical numerics.
#define FMAC8(a0, a1, a2, a3, t, cc, B)                                       \
  asm volatile("v_fmac_f32 %0, %4, %12\n\t"                                   \
               "v_fmac_f32 %1, %5, %13\n\t"                                   \
               "v_fmac_f32 %2, %6, %14\n\t"                                   \
               "v_fmac_f32 %3, %7, %15\n\t"                                   \
               "v_fmac_f32 %0, %8, %16\n\t"                                   \
               "v_fmac_f32 %1, %9, %17\n\t"                                   \
               "v_fmac_f32 %2, %10, %18\n\t"                                  \
               "v_fmac_f32 %3, %11, %19\n\t"                                  \
               : "+v"(a0), "+v"(a1), "+v"(a2), "+v"(a3)                       \
               : "s"(t[0]), "s"(t[1]), "s"(t[2]), "s"(t[3]), "s"(t[4]),       \
                 "s"(t[5]), "s"(t[6]), "s"(t[7]), "v"(cc[B + 0]),             \
                 "v"(cc[B + 1]), "v"(cc[B + 2]), "v"(cc[B + 3]),              \
                 "v"(cc[B + 4]), "v"(cc[B + 5]), "v"(cc[B + 6]),              \
                 "v"(cc[B + 7]))

// One half-scan of the exp-space linear recurrence. Consumes emissions at
// time index t0 + DIR*n for n = 0..N-1. State is the normalized exp-space
// vector (one element per lane); returns the accumulated log offset.
//   PREMUL=false (forward):  broadcast a;   matvec; a = s*E
//   PREMUL=true  (backward): broadcast b*E; matvec; b = s
// Matvec: readlane groups software-pipelined one group ahead of their fmac
// consumers -> every readlane->SGPR->fmac distance is >=15 instructions,
// eliminating the compiler's per-pair hazard s_nops (~440 cy/step in R2/R3).
template <int DIR, bool PREMUL>
__device__ __forceinline__ float scan_half(const float* __restrict__ emj,
                                           int t0, int N, int tmax,
                                           const float (&c)[KSTATES],
                                           float& state) {
  float C = 0.f, r = 1.0f;

  float ring[8];
#pragma unroll
  for (int q = 0; q < 8; ++q) {
    int tq = t0 + DIR * q;
    tq = min(max(tq, 0), tmax);
    ring[q] = emj[(size_t)tq * KSTATES];
  }

  for (int n = 0; n < N; n += 8) {
    float nring[8];
#pragma unroll
    for (int q = 0; q < 8; ++q) {
      int tq = t0 + DIR * (n + 8 + q);
      tq = min(max(tq, 0), tmax);
      nring[q] = emj[(size_t)tq * KSTATES];
    }

    // exp() of the whole chunk up front — off the recurrence chain.
    float Eq[8];
#pragma unroll
    for (int q = 0; q < 8; ++q) Eq[q] = __expf(ring[q]);

#pragma unroll
    for (int q = 0; q < 8; ++q) {
      if (n + q < N) {  // N is wave-uniform -> scalar branch, no divergence
        float E = Eq[q];
        if (q == 0 || q == 4) {  // apply pending renorm exactly once
          E *= r;
          r = 1.0f;
        }

        float av = PREMUL ? state * E : state;

        float acc0 = 0.f, acc1 = 0.f, acc2 = 0.f, acc3 = 0.f;
        float tA[8], tB[8];
        // Software-pipelined: RL group k+1 issues before FMAC group k.
        RL8_FIRST(tA, av, 0);
        RL8(tB, av, 8);
        FMAC8(acc0, acc1, acc2, acc3, tA, c, 0);
        RL8(tA, av, 16);
        FMAC8(acc0, acc1, acc2, acc3, tB, c, 8);
        RL8(tB, av, 24);
        FMAC8(acc0, acc1, acc2, acc3, tA, c, 16);
        RL8(tA, av, 32);
        FMAC8(acc0, acc1, acc2, acc3, tB, c, 24);
        RL8(tB, av, 40);
        FMAC8(acc0, acc1, acc2, acc3, tA, c, 32);
        RL8(tA, av, 48);
        FMAC8(acc0, acc1, acc2, acc3, tB, c, 40);
        RL8(tB, av, 56);
        FMAC8(acc0, acc1, acc2, acc3, tA, c, 48);
        FMAC8(acc0, acc1, acc2, acc3, tB, c, 56);

        float s = (acc0 + acc1) + (acc2 + acc3);
        state = PREMUL ? s : s * E;

        if (q == 3 || q == 7) {  // renorm every 4 steps (off critical path)
          float ar = bcast0(state);
          C += __logf(ar);
          r = __builtin_amdgcn_rcpf(ar);
        }
      }
    }

#pragma unroll
    for (int q = 0; q < 8; ++q) ring[q] = nring[q];
  }

  state *= r;  // fold any pending renorm
  return C;
}

// 2 waves/block: wave 0 runs the forward scan to the meeting point m,
// wave 1 runs the backward scan down to m. Z = sum_j alpha_m[j]*beta_m[j]
// (exact for any m), so the sequential critical path halves: ~1023 -> ~512
// steps. 512 blocks x 2 waves = 4 waves/CU (one per SIMD), each pure-VALU.
__global__ __launch_bounds__(128)
__attribute__((amdgpu_waves_per_eu(1, 1))) void crf_kernel(
    const float* __restrict__ emissions,   // [B, T, K]
    const float* __restrict__ transitions, // [K, K]
    const float* __restrict__ start_trans, // [K]
    const float* __restrict__ end_trans,   // [K]
    const int* __restrict__ labels,        // [B, T]
    const int* __restrict__ sent_len,      // [B]
    float* __restrict__ out,               // scalar
    int T, float inv_B) {
  const int b = blockIdx.x;
  const int tid = threadIdx.x;
  const int wid = tid >> 6;  // 0 = forward wave, 1 = backward wave
  const int j = tid & 63;    // state index == lane
  const int sl = sent_len[b];
  const int tmax = T - 1;

  __shared__ float Afin[KSTATES];  // alpha_m handoff
  __shared__ float Gpart[2];
  __shared__ float Cpart;

  const float* em = emissions + (size_t)b * T * KSTATES;
  const int* lbl = labels + (size_t)b * T;
  const float* emj = em + j;

  // ---- gold score: lane-parallel over time, split across both waves ----
  float g = 0.f;
#pragma unroll 4
  for (int t0 = tid; t0 < T; t0 += 128) {
    if (t0 < sl) {
      int lab = lbl[t0];
      float v = em[(size_t)t0 * KSTATES + lab];
      if (t0 == 0)
        v += start_trans[lab];
      else
        v += transitions[lbl[t0 - 1] * KSTATES + lab];
      if (t0 == sl - 1) v += end_trans[lab];
      g += v;
    }
  }
  float gw = wave_sum64(g);
  if (j == 0) Gpart[wid] = gw;

  const int m = sl >> 1;  // meeting point: fwd ends holding alpha_m

  float state, Coff;
  if (wid == 0) {
    // ---- forward: c[i] = exp(T[i][j]) (column j, coalesced) ----
    float c[KSTATES];
#pragma unroll
    for (int i = 0; i < KSTATES; ++i)
      c[i] = __expf(transitions[i * KSTATES + j]);

    float a0 = start_trans[j] + emj[0];
    float m0 = wave_max64(a0);
    state = __expf(a0 - m0);
    // consume emissions t = 1..m  -> state ~ alpha_m (normalized)
    Coff = m0 + scan_half<1, false>(emj, 1, m, tmax, c, state);
  } else {
    // ---- backward: c[i] = exp(T[j][i]) (row j; 16KB matrix, L1-resident) ----
    float c[KSTATES];
#pragma unroll
    for (int i = 0; i < KSTATES; ++i)
      c[i] = __expf(transitions[j * KSTATES + i]);

    float b0 = end_trans[j];
    float mb = wave_max64(b0);
    state = __expf(b0 - mb);
    // consume emissions t = sl-1 down to m+1 -> state ~ beta_m (normalized)
    Coff = mb + scan_half<-1, true>(emj, sl - 1, sl - 1 - m, tmax, c, state);
  }

  if (wid == 0) {
    Afin[j] = state;
    if (j == 0) Cpart = Coff;
  }
  __syncthreads();

  if (wid == 1) {
    // Z = sum_j alpha_m[j] * beta_m[j]
    float v = Afin[j] * state;
    float sum = wave_sum64(v);
    float fwd = Cpart + Coff + __logf(sum);
    if (j == 0) atomicAdd(out, (fwd - Gpart[0] - Gpart[1]) * inv_B);
  }
}

extern "C" void kernel_launch(void* const* d_in, const int* in_sizes, int n_in,
                              void* d_out, int out_size, void* d_ws,
                              size_t ws_size, hipStream_t stream) {
  const float* emissions = (const float*)d_in[0];
  const float* transitions = (const float*)d_in[1];
  const float* start_trans = (const float*)d_in[2];
  const float* end_trans = (const float*)d_in[3];
  const int* labels = (const int*)d_in[4];
  const int* sent_len = (const int*)d_in[5];
  float* out = (float*)d_out;

  const int B = in_sizes[5];
  const int T = in_sizes[4] / B;

  hipMemsetAsync(out, 0, sizeof(float), stream);
  crf_kernel<<<B, 128, 0, stream>>>(emissions, transitions, start_trans,
                                    end_trans, labels, sent_len, out, T,
                                    1.0f / (float)B);
}